// Round 7
// baseline (1137.653 us; speedup 1.0000x reference)
//
#include <hip/hip_runtime.h>
#include <math.h>

#define NUM_BASIS 8
#define SQRT3 1.7320508075688772f
#define SQRT2 1.4142135623730951f
#define INV_SQRT_DEG 0.17677669529663687f   // 1/sqrt(32)
#define PI_F 3.14159265358979323846f

typedef _Float16 half8 __attribute__((ext_vector_type(8)));
typedef float float4v __attribute__((ext_vector_type(4)));

__device__ __forceinline__ float sigmoidf_(float x) { return 1.0f / (1.0f + __expf(-x)); }
__device__ __forceinline__ float siluf_(float x) { return x * sigmoidf_(x); }

// ---------------------------------------------------------------------------
// CSR build: degree count -> single-block shfl scan -> fused geometry+scatter
// ---------------------------------------------------------------------------
__global__ __launch_bounds__(256) void count_deg(
    const int* __restrict__ dst, int* __restrict__ deg, int E)
{
    int e = blockIdx.x * blockDim.x + threadIdx.x;
    if (e < E) atomicAdd(&deg[dst[e]], 1);
}

__global__ __launch_bounds__(1024) void scan_deg(
    const int* __restrict__ deg, int* __restrict__ cursor, int N)
{
    __shared__ int wsum[16];
    __shared__ int carry_s, tot_s;
    int tid = threadIdx.x;
    int wid = tid >> 6, lane = tid & 63;
    if (tid == 0) carry_s = 0;
    __syncthreads();
    for (int base = 0; base < N; base += 1024) {
        int i = base + tid;
        int v = (i < N) ? deg[i] : 0;
        int incl = v;
        #pragma unroll
        for (int off = 1; off < 64; off <<= 1) {
            int t = __shfl_up(incl, off);
            if (lane >= off) incl += t;
        }
        if (lane == 63) wsum[wid] = incl;
        __syncthreads();
        if (wid == 0 && lane < 16) {
            int wv = wsum[lane];
            int wincl = wv;
            #pragma unroll
            for (int off = 1; off < 16; off <<= 1) {
                int t = __shfl_up(wincl, off);
                if (lane >= off) wincl += t;
            }
            wsum[lane] = wincl - wv;        // exclusive wave offset
            if (lane == 15) tot_s = wincl;  // chunk total
        }
        __syncthreads();
        int carry = carry_s;
        if (i < N) cursor[i] = carry + wsum[wid] + incl - v;
        __syncthreads();
        if (tid == 0) carry_s = carry + tot_s;
        __syncthreads();
    }
}

// Per-edge geometry + radial embedding, scattered directly into CSR slots.
__global__ __launch_bounds__(256) void edge_pre_scatter(
    const float* __restrict__ pos, const int* __restrict__ src,
    const int* __restrict__ dst, const float* __restrict__ cs,
    const float* __restrict__ cell, const int* __restrict__ img,
    int* __restrict__ cursor, float* __restrict__ emb,
    float4* __restrict__ y14, int* __restrict__ srcp,
    int* __restrict__ dstp, int E)
{
    int e = blockIdx.x * blockDim.x + threadIdx.x;
    if (e >= E) return;
    int si = src[e], di = dst[e];
    int slot = atomicAdd(&cursor[di], 1);
    srcp[slot] = si;
    dstp[slot] = di;
    float vx = pos[di*3+0] - pos[si*3+0];
    float vy = pos[di*3+1] - pos[si*3+1];
    float vz = pos[di*3+2] - pos[si*3+2];
    float c0 = cs[(size_t)e*3+0], c1 = cs[(size_t)e*3+1], c2 = cs[(size_t)e*3+2];
    const float* M = cell + (size_t)img[si] * 9;
    vx += c0*M[0] + c1*M[3] + c2*M[6];
    vy += c0*M[1] + c1*M[4] + c2*M[7];
    vz += c0*M[2] + c1*M[5] + c2*M[8];
    float r  = sqrtf(vx*vx + vy*vy + vz*vz);
    float rs = fmaxf(r, 1e-9f);
    float inv = 1.0f / rs;
    y14[slot] = make_float4(SQRT3*vx*inv, SQRT3*vy*inv, SQRT3*vz*inv, 0.0f);
    // polynomial cutoff p=6: 1 - 28 x^6 + 48 x^7 - 21 x^8 (0 for x>=1)
    float x = r * (1.0f / 5.0f);
    float x2 = x*x, x6 = x2*x2*x2;
    float fc = 1.0f - 28.0f*x6 + 48.0f*x6*x - 21.0f*x6*x2;
    if (x >= 1.0f) fc = 0.0f;
    float pre = sqrtf(2.0f / 5.0f) * inv * fc;
    float t = PI_F * rs * (1.0f / 5.0f);
    #pragma unroll
    for (int n = 1; n <= NUM_BASIS; n++)
        emb[(size_t)slot*NUM_BASIS + (n-1)] = pre * __sinf((float)n * t);
}

// ---------------------------------------------------------------------------
// W2 (3,64,320) fp32 -> f16 MFMA B-fragment order; also wl12 = Wl1 @ Wl2.
// w2f[((((L*4+cg)*5+p)*2+kh)*64+lane)*8+j] = W2[L][k][n]
//   k = kh*32 + (lane>>4)*8 + j,  n = p*64 + cg*16 + (lane&15)
// ---------------------------------------------------------------------------
__global__ __launch_bounds__(256) void transpose_w2f(
    const float* __restrict__ W2, _Float16* __restrict__ w2f,
    const float* __restrict__ Wl1, const float* __restrict__ Wl2,
    float* __restrict__ wl12)
{
    int idx = blockIdx.x * blockDim.x + threadIdx.x;
    if (idx < 64) {
        float a = 0.f;
        #pragma unroll
        for (int j = 0; j < 16; j++) a = fmaf(Wl1[idx*16 + j], Wl2[j], a);
        wl12[idx] = a;
    }
    if (idx >= 3 * 20480) return;
    int L  = idx / 20480;
    int r  = idx % 20480;
    int cg = r / 5120;
    int r2 = r % 5120;
    int p  = r2 / 1024;
    int r3 = r2 % 1024;
    int kh = r3 / 512;
    int r4 = r3 % 512;
    int lane = r4 / 8;
    int j  = r4 % 8;
    int k = kh*32 + (lane >> 4)*8 + j;
    int n = p*64 + cg*16 + (lane & 15);
    w2f[idx] = (_Float16)W2[(size_t)L*20480 + k*320 + n];
}

// ---------------------------------------------------------------------------
// nf[n*64 + c] = (s, vx, vy, vz) AoS. Init s from w_lin_in, v = 0.
// ---------------------------------------------------------------------------
__global__ __launch_bounds__(256) void node_init(
    const int* __restrict__ type, const float* __restrict__ wlin,
    float4* __restrict__ nf, int N)
{
    int i = blockIdx.x * blockDim.x + threadIdx.x;
    if (i >= N * 64) return;
    int n = i >> 6, c = i & 63;
    nf[i] = make_float4(wlin[(size_t)type[n]*64 + c], 0.f, 0.f, 0.f);
}

// ---------------------------------------------------------------------------
// MFMA edge kernel: one wave per 64 CSR-consecutive edges (4 tiles of 16).
// Per tile: h in A-frag layout, W2 f16 B-frags, 40 MFMA; messages + segmented
// reduction in C-layout. Cross-tile per-channel carry in registers => tail
// atomics only at true dst-segment ends. cg loop FULLY unrolled so carry
// arrays stay in static VGPRs. Do NOT cap VGPRs (R4 spill catastrophe).
// ---------------------------------------------------------------------------
__global__ __launch_bounds__(256) void edge_msg_mfma(
    const float* __restrict__ emb, const float4* __restrict__ y14,
    const int* __restrict__ srcp, const int* __restrict__ dstp,
    const float4* __restrict__ nf,
    const float* __restrict__ W1, const float* __restrict__ B1,
    const _Float16* __restrict__ w2f,
    float* __restrict__ agg, int E)
{
    int grp   = (blockIdx.x * blockDim.x + threadIdx.x) >> 6;
    int lane  = threadIdx.x & 63;
    int gbase = grp * 64;
    if (gbase >= E) return;
    int q   = lane >> 4;     // quad
    int col = lane & 15;     // channel-in-group / A-edge col

    float CTs[4] = {0,0,0,0}, CTx[4] = {0,0,0,0};
    float CTy[4] = {0,0,0,0}, CTz[4] = {0,0,0,0};
    int prev_dlast = -1;     // dst of last edge of previous tile

    #pragma unroll 1
    for (int t = 0; t < 4; t++) {
        int wbase = gbase + t*16;
        if (wbase >= E) break;

        // ---- A-fragments: h[k] for edge (wbase+col), k = kh*32 + q*8 + j ----
        half8 afrag[2];
        {
            int eA = wbase + col;
            if (eA >= E) eA = E - 1;
            float4 ea  = *(const float4*)(emb + (size_t)eA*8);
            float4 eb2 = *(const float4*)(emb + (size_t)eA*8 + 4);
            float em[8] = {ea.x, ea.y, ea.z, ea.w, eb2.x, eb2.y, eb2.z, eb2.w};
            #pragma unroll
            for (int kh = 0; kh < 2; kh++) {
                int kb = kh*32 + q*8;
                float hv[8];
                float4 b0 = *(const float4*)(B1 + kb);
                float4 b1 = *(const float4*)(B1 + kb + 4);
                hv[0]=b0.x; hv[1]=b0.y; hv[2]=b0.z; hv[3]=b0.w;
                hv[4]=b1.x; hv[5]=b1.y; hv[6]=b1.z; hv[7]=b1.w;
                #pragma unroll
                for (int jj = 0; jj < 8; jj++) {
                    float4 wa = *(const float4*)(W1 + jj*64 + kb);
                    float4 wb = *(const float4*)(W1 + jj*64 + kb + 4);
                    hv[0] = fmaf(em[jj], wa.x, hv[0]);
                    hv[1] = fmaf(em[jj], wa.y, hv[1]);
                    hv[2] = fmaf(em[jj], wa.z, hv[2]);
                    hv[3] = fmaf(em[jj], wa.w, hv[3]);
                    hv[4] = fmaf(em[jj], wb.x, hv[4]);
                    hv[5] = fmaf(em[jj], wb.y, hv[5]);
                    hv[6] = fmaf(em[jj], wb.z, hv[6]);
                    hv[7] = fmaf(em[jj], wb.w, hv[7]);
                }
                #pragma unroll
                for (int j = 0; j < 8; j++)
                    afrag[kh][j] = (_Float16)siluf_(hv[j]);
            }
        }

        // ---- per-quad edge metadata (4 edges eb..eb+3) ----
        int eb = wbase + q*4;
        int d[4], si[4];
        float4 y1v[4];
        #pragma unroll
        for (int r = 0; r < 4; r++) {
            int ee = eb + r;
            bool vr = ee < E;
            int ec = vr ? ee : (E - 1);
            d[r]   = vr ? dstp[ec] : -1;
            si[r]  = srcp[ec];
            y1v[r] = y14[ec];
        }
        int dnq = __shfl_down(d[0], 16);          // next quad's first dst
        int nt = wbase + 16;
        int d_next_tile = (t < 3 && nt < E) ? dstp[nt] : -1;
        int nd3 = (q == 3) ? d_next_tile : dnq;
        int df = d[0], dl = d[3];
        bool U = (df == dl);
        int dlp = __shfl_up(dl, 16);
        bool link = (q > 0) && (dlp == df);
        int d_first   = __shfl(d[0], 0);
        bool ctvalid  = (q == 0) && (prev_dlast >= 0) && (prev_dlast == d_first);
        int dlast_tile = __shfl(d[3], 48);

        // ---- channel groups (FULLY unrolled: carry regs must stay static) ----
        #pragma unroll
        for (int cg = 0; cg < 4; cg++) {
            float4v acc[5];
            #pragma unroll
            for (int p = 0; p < 5; p++) acc[p] = (float4v){0.f, 0.f, 0.f, 0.f};
            const _Float16* wbp = w2f + ((size_t)cg*5*2*64*8) + (size_t)lane*8;
            #pragma unroll
            for (int p = 0; p < 5; p++) {
                half8 bf0 = *(const half8*)(wbp + ((size_t)(p*2 + 0))*64*8);
                half8 bf1 = *(const half8*)(wbp + ((size_t)(p*2 + 1))*64*8);
                acc[p] = __builtin_amdgcn_mfma_f32_16x16x32_f16(afrag[0], bf0, acc[p], 0, 0, 0);
                acc[p] = __builtin_amdgcn_mfma_f32_16x16x32_f16(afrag[1], bf1, acc[p], 0, 0, 0);
            }
            int c = cg*16 + col;

            float ms[4], mx[4], my[4], mz[4];
            #pragma unroll
            for (int r = 0; r < 4; r++) {
                float4 f = nf[(size_t)si[r]*64 + c];
                float yx = y1v[r].x, yy = y1v[r].y, yz = y1v[r].z;
                float w1 = acc[0][r], w2 = acc[1][r], w3 = acc[2][r];
                float w4 = acc[3][r], w5 = acc[4][r];
                float vdoty = f.y*yx + f.z*yy + f.w*yz;
                ms[r] = w1*f.x + w2*vdoty*(1.0f/SQRT3);
                float cx = f.z*yz - f.w*yy;
                float cy = f.w*yx - f.y*yz;
                float cz = f.y*yy - f.z*yx;
                mx[r] = w3*f.x*yx + w4*f.y + w5*cx*(1.0f/SQRT2);
                my[r] = w3*f.x*yy + w4*f.z + w5*cy*(1.0f/SQRT2);
                mz[r] = w3*f.x*yz + w4*f.w + w5*cz*(1.0f/SQRT2);
            }
            // in-lane segmented inclusive scan over the 4 reg-edges
            #pragma unroll
            for (int r = 1; r < 4; r++) {
                if (d[r] == d[r-1]) {
                    ms[r] += ms[r-1]; mx[r] += mx[r-1];
                    my[r] += my[r-1]; mz[r] += mz[r-1];
                }
            }
            // cross-quad chain; quad 0 seeded with cross-tile carry
            float b0s = ctvalid ? CTs[cg] : 0.f;
            float b0x = ctvalid ? CTx[cg] : 0.f;
            float b0y = ctvalid ? CTy[cg] : 0.f;
            float b0z = ctvalid ? CTz[cg] : 0.f;
            float Cs = b0s, Cx = b0x, Cy = b0y, Cz = b0z;
            #pragma unroll
            for (int it = 0; it < 3; it++) {
                float es = ms[3] + (U ? Cs : 0.f);
                float ex = mx[3] + (U ? Cx : 0.f);
                float ey = my[3] + (U ? Cy : 0.f);
                float ez = mz[3] + (U ? Cz : 0.f);
                float ts = __shfl_up(es, 16);
                float tx = __shfl_up(ex, 16);
                float ty = __shfl_up(ey, 16);
                float tz = __shfl_up(ez, 16);
                Cs = link ? ts : b0s; Cx = link ? tx : b0x;
                Cy = link ? ty : b0y; Cz = link ? tz : b0z;
            }
            // final values + tail atomics; capture r=3 value for carry
            float last_fs = 0.f, last_fx = 0.f, last_fy = 0.f, last_fz = 0.f;
            bool hr = true;
            #pragma unroll
            for (int r = 0; r < 4; r++) {
                if (r > 0) hr = hr && (d[r] == d[r-1]);
                float fs = ms[r] + (hr ? Cs : 0.f);
                float fx = mx[r] + (hr ? Cx : 0.f);
                float fy = my[r] + (hr ? Cy : 0.f);
                float fz = mz[r] + (hr ? Cz : 0.f);
                if (r == 3) { last_fs = fs; last_fx = fx; last_fy = fy; last_fz = fz; }
                int nd = (r < 3) ? d[r+1] : nd3;
                if (nd != d[r] && d[r] >= 0) {
                    float* ab = agg + ((size_t)d[r]*64 + c)*4;
                    atomicAdd(ab + 0, fs);
                    atomicAdd(ab + 1, fx);
                    atomicAdd(ab + 2, fy);
                    atomicAdd(ab + 3, fz);
                }
            }
            // carry for next tile comes from the q3 lane with same col
            CTs[cg] = __shfl(last_fs, 48 + col);
            CTx[cg] = __shfl(last_fx, 48 + col);
            CTy[cg] = __shfl(last_fy, 48 + col);
            CTz[cg] = __shfl(last_fz, 48 + col);
        }
        prev_dlast = dlast_tile;
    }
}

// ---------------------------------------------------------------------------
// Gated self-interaction + resnet; last layer fuses the energy projection
// (s@Wl1)@Wl2 == s . wl12. One wave per node, lane = channel.
// ---------------------------------------------------------------------------
__global__ __launch_bounds__(256) void node_update(
    float4* __restrict__ nf, const float4* __restrict__ agg,
    const float* __restrict__ Wg, const float* __restrict__ Ws,
    const float* __restrict__ Wv, const float* __restrict__ wl12,
    float* __restrict__ out, int do_out, int N)
{
    int wid  = (blockIdx.x * blockDim.x + threadIdx.x) >> 6;
    int lane = threadIdx.x & 63;
    if (wid >= N) return;
    size_t base = (size_t)wid * 64;
    float4 av = agg[base + lane];
    float a0 = av.x * INV_SQRT_DEG;
    float ax = av.y * INV_SQRT_DEG;
    float ay = av.z * INV_SQRT_DEG;
    float az = av.w * INV_SQRT_DEG;
    float g = 0.f, ss = 0.f, ox = 0.f, oy = 0.f, oz = 0.f;
    #pragma unroll 4
    for (int c = 0; c < 64; c++) {
        float a  = __shfl(a0, c);
        float bx = __shfl(ax, c);
        float by = __shfl(ay, c);
        float bz = __shfl(az, c);
        float wg = Wg[c*64 + lane];
        float ws = Ws[c*64 + lane];
        float wv = Wv[c*64 + lane];
        g  = fmaf(a,  wg, g);
        ss = fmaf(a,  ws, ss);
        ox = fmaf(bx, wv, ox);
        oy = fmaf(by, wv, oy);
        oz = fmaf(bz, wv, oz);
    }
    float gate = sigmoidf_(g);
    float4 cur = nf[base + lane];
    cur.x += siluf_(ss);
    cur.y += ox * gate;
    cur.z += oy * gate;
    cur.w += oz * gate;
    nf[base + lane] = cur;
    if (do_out) {
        float contrib = cur.x * wl12[lane];
        #pragma unroll
        for (int off = 32; off; off >>= 1)
            contrib += __shfl_xor(contrib, off);
        if (lane == 0) out[wid] = contrib;
    }
}

extern "C" void kernel_launch(void* const* d_in, const int* in_sizes, int n_in,
                              void* d_out, int out_size, void* d_ws, size_t ws_size,
                              hipStream_t stream)
{
    const int*   atom_type = (const int*)  d_in[0];
    const float* pos       = (const float*)d_in[1];
    const int*   src       = (const int*)  d_in[2];
    const int*   dst       = (const int*)  d_in[3];
    const float* cs        = (const float*)d_in[4];
    const float* cell      = (const float*)d_in[5];
    const int*   img       = (const int*)  d_in[6];
    const float* wlin_in   = (const float*)d_in[7];
    const float* mw1       = (const float*)d_in[8];
    const float* mb1       = (const float*)d_in[9];
    const float* mw2       = (const float*)d_in[10];
    const float* wss       = (const float*)d_in[11];
    const float* wsv       = (const float*)d_in[12];
    const float* wg        = (const float*)d_in[13];
    const float* wl1       = (const float*)d_in[14];
    const float* wl2       = (const float*)d_in[15];
    int N = in_sizes[0];
    int E = in_sizes[2];

    char* w = (char*)d_ws;
    float*  emb  = (float*)w;  w += (size_t)E * 8 * sizeof(float);     // 16.4 MB
    float4* y14  = (float4*)w; w += (size_t)E * sizeof(float4);        //  8.2 MB
    int*    srcp = (int*)w;    w += (size_t)E * sizeof(int);           //  2.0 MB
    int*    dstp = (int*)w;    w += (size_t)E * sizeof(int);           //  2.0 MB
    float4* nf   = (float4*)w; w += (size_t)N * 64 * sizeof(float4);   // 16.4 MB
    float4* agg  = (float4*)w; w += (size_t)N * 64 * sizeof(float4);   // 16.4 MB
    _Float16* w2f = (_Float16*)w; w += (size_t)3 * 20480 * sizeof(_Float16);
    float*  wl12 = (float*)w;  w += 64 * sizeof(float);
    int*    deg  = (int*)w;    w += (size_t)N * sizeof(int);
    int*    curs = (int*)w;    w += (size_t)N * sizeof(int);

    hipMemsetAsync(deg, 0, (size_t)N * sizeof(int), stream);

    count_deg<<<(E + 255) / 256, 256, 0, stream>>>(dst, deg, E);
    scan_deg<<<1, 1024, 0, stream>>>(deg, curs, N);
    transpose_w2f<<<(3 * 20480 + 255) / 256, 256, 0, stream>>>(
        mw2, w2f, wl1, wl2, wl12);
    edge_pre_scatter<<<(E + 255) / 256, 256, 0, stream>>>(
        pos, src, dst, cs, cell, img, curs, emb, y14, srcp, dstp, E);
    node_init<<<(N * 64 + 255) / 256, 256, 0, stream>>>(atom_type, wlin_in, nf, N);

    int nblocks = (E + 255) / 256;   // 256 threads = 4 waves = 256 edges/block
    for (int L = 0; L < 3; L++) {
        hipMemsetAsync(agg, 0, (size_t)N * 64 * sizeof(float4), stream);
        edge_msg_mfma<<<nblocks, 256, 0, stream>>>(
            emb, y14, srcp, dstp, nf,
            mw1 + L * 8 * 64, mb1 + L * 64, w2f + (size_t)L * 20480,
            (float*)agg, E);
        node_update<<<(N * 64 + 255) / 256, 256, 0, stream>>>(
            nf, agg, wg + L * 4096, wss + L * 4096, wsv + L * 4096,
            wl12, (float*)d_out, (L == 2) ? 1 : 0, N);
    }
}

// Round 8
// 884.907 us; speedup vs baseline: 1.2856x; 1.2856x over previous
//
#include <hip/hip_runtime.h>
#include <math.h>

#define NUM_BASIS 8
#define SQRT3 1.7320508075688772f
#define SQRT2 1.4142135623730951f
#define INV_SQRT_DEG 0.17677669529663687f   // 1/sqrt(32)
#define PI_F 3.14159265358979323846f

typedef _Float16 half8 __attribute__((ext_vector_type(8)));
typedef float float4v __attribute__((ext_vector_type(4)));

__device__ __forceinline__ float sigmoidf_(float x) { return 1.0f / (1.0f + __expf(-x)); }
__device__ __forceinline__ float siluf_(float x) { return x * sigmoidf_(x); }

// ---------------------------------------------------------------------------
// CSR build: degree count -> single-block shfl scan -> fused geometry+scatter
// ---------------------------------------------------------------------------
__global__ __launch_bounds__(256) void count_deg(
    const int* __restrict__ dst, int* __restrict__ deg, int E)
{
    int e = blockIdx.x * blockDim.x + threadIdx.x;
    if (e < E) atomicAdd(&deg[dst[e]], 1);
}

__global__ __launch_bounds__(1024) void scan_deg(
    const int* __restrict__ deg, int* __restrict__ cursor, int N)
{
    __shared__ int wsum[16];
    __shared__ int carry_s, tot_s;
    int tid = threadIdx.x;
    int wid = tid >> 6, lane = tid & 63;
    if (tid == 0) carry_s = 0;
    __syncthreads();
    for (int base = 0; base < N; base += 1024) {
        int i = base + tid;
        int v = (i < N) ? deg[i] : 0;
        int incl = v;
        #pragma unroll
        for (int off = 1; off < 64; off <<= 1) {
            int t = __shfl_up(incl, off);
            if (lane >= off) incl += t;
        }
        if (lane == 63) wsum[wid] = incl;
        __syncthreads();
        if (wid == 0 && lane < 16) {
            int wv = wsum[lane];
            int wincl = wv;
            #pragma unroll
            for (int off = 1; off < 16; off <<= 1) {
                int t = __shfl_up(wincl, off);
                if (lane >= off) wincl += t;
            }
            wsum[lane] = wincl - wv;        // exclusive wave offset
            if (lane == 15) tot_s = wincl;  // chunk total
        }
        __syncthreads();
        int carry = carry_s;
        if (i < N) cursor[i] = carry + wsum[wid] + incl - v;
        __syncthreads();
        if (tid == 0) carry_s = carry + tot_s;
        __syncthreads();
    }
}

// Per-edge geometry + radial embedding, scattered directly into CSR slots.
__global__ __launch_bounds__(256) void edge_pre_scatter(
    const float* __restrict__ pos, const int* __restrict__ src,
    const int* __restrict__ dst, const float* __restrict__ cs,
    const float* __restrict__ cell, const int* __restrict__ img,
    int* __restrict__ cursor, float* __restrict__ emb,
    float4* __restrict__ y14, int* __restrict__ srcp,
    int* __restrict__ dstp, int E)
{
    int e = blockIdx.x * blockDim.x + threadIdx.x;
    if (e >= E) return;
    int si = src[e], di = dst[e];
    int slot = atomicAdd(&cursor[di], 1);
    srcp[slot] = si;
    dstp[slot] = di;
    float vx = pos[di*3+0] - pos[si*3+0];
    float vy = pos[di*3+1] - pos[si*3+1];
    float vz = pos[di*3+2] - pos[si*3+2];
    float c0 = cs[(size_t)e*3+0], c1 = cs[(size_t)e*3+1], c2 = cs[(size_t)e*3+2];
    const float* M = cell + (size_t)img[si] * 9;
    vx += c0*M[0] + c1*M[3] + c2*M[6];
    vy += c0*M[1] + c1*M[4] + c2*M[7];
    vz += c0*M[2] + c1*M[5] + c2*M[8];
    float r  = sqrtf(vx*vx + vy*vy + vz*vz);
    float rs = fmaxf(r, 1e-9f);
    float inv = 1.0f / rs;
    y14[slot] = make_float4(SQRT3*vx*inv, SQRT3*vy*inv, SQRT3*vz*inv, 0.0f);
    // polynomial cutoff p=6: 1 - 28 x^6 + 48 x^7 - 21 x^8 (0 for x>=1)
    float x = r * (1.0f / 5.0f);
    float x2 = x*x, x6 = x2*x2*x2;
    float fc = 1.0f - 28.0f*x6 + 48.0f*x6*x - 21.0f*x6*x2;
    if (x >= 1.0f) fc = 0.0f;
    float pre = sqrtf(2.0f / 5.0f) * inv * fc;
    float t = PI_F * rs * (1.0f / 5.0f);
    #pragma unroll
    for (int n = 1; n <= NUM_BASIS; n++)
        emb[(size_t)slot*NUM_BASIS + (n-1)] = pre * __sinf((float)n * t);
}

// ---------------------------------------------------------------------------
// W2 (3,64,320) fp32 -> f16 MFMA B-fragment order; also wl12 = Wl1 @ Wl2.
// w2f[((((L*4+cg)*5+p)*2+kh)*64+lane)*8+j] = W2[L][k][n]
//   k = kh*32 + (lane>>4)*8 + j,  n = p*64 + cg*16 + (lane&15)
// ---------------------------------------------------------------------------
__global__ __launch_bounds__(256) void transpose_w2f(
    const float* __restrict__ W2, _Float16* __restrict__ w2f,
    const float* __restrict__ Wl1, const float* __restrict__ Wl2,
    float* __restrict__ wl12)
{
    int idx = blockIdx.x * blockDim.x + threadIdx.x;
    if (idx < 64) {
        float a = 0.f;
        #pragma unroll
        for (int j = 0; j < 16; j++) a = fmaf(Wl1[idx*16 + j], Wl2[j], a);
        wl12[idx] = a;
    }
    if (idx >= 3 * 20480) return;
    int L  = idx / 20480;
    int r  = idx % 20480;
    int cg = r / 5120;
    int r2 = r % 5120;
    int p  = r2 / 1024;
    int r3 = r2 % 1024;
    int kh = r3 / 512;
    int r4 = r3 % 512;
    int lane = r4 / 8;
    int j  = r4 % 8;
    int k = kh*32 + (lane >> 4)*8 + j;
    int n = p*64 + cg*16 + (lane & 15);
    w2f[idx] = (_Float16)W2[(size_t)L*20480 + k*320 + n];
}

// ---------------------------------------------------------------------------
// nf[n*64 + c] = (s, vx, vy, vz) AoS. Init s from w_lin_in, v = 0.
// ---------------------------------------------------------------------------
__global__ __launch_bounds__(256) void node_init(
    const int* __restrict__ type, const float* __restrict__ wlin,
    float4* __restrict__ nf, int N)
{
    int i = blockIdx.x * blockDim.x + threadIdx.x;
    if (i >= N * 64) return;
    int n = i >> 6, c = i & 63;
    nf[i] = make_float4(wlin[(size_t)type[n]*64 + c], 0.f, 0.f, 0.f);
}

// ---------------------------------------------------------------------------
// MFMA edge kernel: one wave per 16 CSR-consecutive edges (R6 operating
// point: VGPR~60, ~40% occupancy — latency-hiding beats per-wave efficiency;
// R7's 64-edge/wave variant regressed 46% via VGPR=160/occ=11%).
// A (16 edges x 64 k) = h computed per-lane directly in A-frag layout (f16).
// B = W2 f16 fragments from w2f (coalesced 16B/lane vector loads).
// D lane layout: col=lane&15 -> channel within group, row=quad*4+reg -> edge.
// Message math + segmented reduction in C-layout; tails atomicAdd.
// Do NOT cap VGPRs (R4: spill catastrophe).
// ---------------------------------------------------------------------------
__global__ __launch_bounds__(256) void edge_msg_mfma(
    const float* __restrict__ emb, const float4* __restrict__ y14,
    const int* __restrict__ srcp, const int* __restrict__ dstp,
    const float4* __restrict__ nf,
    const float* __restrict__ W1, const float* __restrict__ B1,
    const _Float16* __restrict__ w2f,
    float* __restrict__ agg, int E)
{
    int wave  = (blockIdx.x * blockDim.x + threadIdx.x) >> 6;
    int lane  = threadIdx.x & 63;
    int wbase = wave * 16;
    if (wbase >= E) return;
    int q   = lane >> 4;     // quad: selects 4-edge row group / k-slice
    int col = lane & 15;     // column: A-edge index / output channel idx

    // ---- A-fragments: h[k] for edge (wbase+col), k = kh*32 + q*8 + j ----
    half8 afrag[2];
    {
        int eA = wbase + col;
        float4 ea = *(const float4*)(emb + (size_t)eA*8);
        float4 eb2 = *(const float4*)(emb + (size_t)eA*8 + 4);
        float em[8] = {ea.x, ea.y, ea.z, ea.w, eb2.x, eb2.y, eb2.z, eb2.w};
        #pragma unroll
        for (int kh = 0; kh < 2; kh++) {
            int kb = kh*32 + q*8;
            float hv[8];
            float4 b0 = *(const float4*)(B1 + kb);
            float4 b1 = *(const float4*)(B1 + kb + 4);
            hv[0]=b0.x; hv[1]=b0.y; hv[2]=b0.z; hv[3]=b0.w;
            hv[4]=b1.x; hv[5]=b1.y; hv[6]=b1.z; hv[7]=b1.w;
            #pragma unroll
            for (int jj = 0; jj < 8; jj++) {
                float4 wa = *(const float4*)(W1 + jj*64 + kb);
                float4 wb = *(const float4*)(W1 + jj*64 + kb + 4);
                hv[0] = fmaf(em[jj], wa.x, hv[0]);
                hv[1] = fmaf(em[jj], wa.y, hv[1]);
                hv[2] = fmaf(em[jj], wa.z, hv[2]);
                hv[3] = fmaf(em[jj], wa.w, hv[3]);
                hv[4] = fmaf(em[jj], wb.x, hv[4]);
                hv[5] = fmaf(em[jj], wb.y, hv[5]);
                hv[6] = fmaf(em[jj], wb.z, hv[6]);
                hv[7] = fmaf(em[jj], wb.w, hv[7]);
            }
            #pragma unroll
            for (int j = 0; j < 8; j++)
                afrag[kh][j] = (_Float16)siluf_(hv[j]);
        }
    }

    // ---- per-quad edge metadata (4 edges eb..eb+3, same for 16 lanes) ----
    int eb = wbase + q*4;
    int d[4], si[4];
    float4 y1v[4];
    #pragma unroll
    for (int r = 0; r < 4; r++) {
        d[r]   = dstp[eb + r];
        si[r]  = srcp[eb + r];
        y1v[r] = y14[eb + r];
    }
    int dnq = __shfl_down(d[0], 16);      // next quad's first dst
    int nd3 = (q == 3) ? -1 : dnq;        // q3 reg3: forced tail (cross-wave via atomic)
    int df = d[0], dl = d[3];
    bool U = (df == dl);
    int dlp = __shfl_up(dl, 16);
    bool link = (q > 0) && (dlp == df);

    // ---- channel groups of 16 ----
    #pragma unroll 1
    for (int cg = 0; cg < 4; cg++) {
        float4v acc[5];
        #pragma unroll
        for (int p = 0; p < 5; p++) acc[p] = (float4v){0.f, 0.f, 0.f, 0.f};
        const _Float16* wbp = w2f + ((size_t)cg*5*2*64*8) + (size_t)lane*8;
        #pragma unroll
        for (int p = 0; p < 5; p++) {
            half8 bf0 = *(const half8*)(wbp + ((size_t)(p*2 + 0))*64*8);
            half8 bf1 = *(const half8*)(wbp + ((size_t)(p*2 + 1))*64*8);
            acc[p] = __builtin_amdgcn_mfma_f32_16x16x32_f16(afrag[0], bf0, acc[p], 0, 0, 0);
            acc[p] = __builtin_amdgcn_mfma_f32_16x16x32_f16(afrag[1], bf1, acc[p], 0, 0, 0);
        }
        int c = cg*16 + col;

        // message math per reg-edge (C-layout: acc[p][r] = w_p(edge eb+r, c))
        float ms[4], mx[4], my[4], mz[4];
        #pragma unroll
        for (int r = 0; r < 4; r++) {
            float4 f = nf[(size_t)si[r]*64 + c];
            float yx = y1v[r].x, yy = y1v[r].y, yz = y1v[r].z;
            float w1 = acc[0][r], w2 = acc[1][r], w3 = acc[2][r];
            float w4 = acc[3][r], w5 = acc[4][r];
            float vdoty = f.y*yx + f.z*yy + f.w*yz;
            ms[r] = w1*f.x + w2*vdoty*(1.0f/SQRT3);
            float cx = f.z*yz - f.w*yy;
            float cy = f.w*yx - f.y*yz;
            float cz = f.y*yy - f.z*yx;
            mx[r] = w3*f.x*yx + w4*f.y + w5*cx*(1.0f/SQRT2);
            my[r] = w3*f.x*yy + w4*f.z + w5*cy*(1.0f/SQRT2);
            mz[r] = w3*f.x*yz + w4*f.w + w5*cz*(1.0f/SQRT2);
        }
        // in-lane segmented inclusive scan over the 4 reg-edges
        #pragma unroll
        for (int r = 1; r < 4; r++) {
            if (d[r] == d[r-1]) {
                ms[r] += ms[r-1]; mx[r] += mx[r-1];
                my[r] += my[r-1]; mz[r] += mz[r-1];
            }
        }
        // cross-quad carry (chains up to 4 quads -> 3 iterations)
        float Cs = 0.f, Cx = 0.f, Cy = 0.f, Cz = 0.f;
        #pragma unroll
        for (int it = 0; it < 3; it++) {
            float es = ms[3] + (U ? Cs : 0.f);
            float ex = mx[3] + (U ? Cx : 0.f);
            float ey = my[3] + (U ? Cy : 0.f);
            float ez = mz[3] + (U ? Cz : 0.f);
            float ts = __shfl_up(es, 16);
            float tx = __shfl_up(ex, 16);
            float ty = __shfl_up(ey, 16);
            float tz = __shfl_up(ez, 16);
            Cs = link ? ts : 0.f; Cx = link ? tx : 0.f;
            Cy = link ? ty : 0.f; Cz = link ? tz : 0.f;
        }
        // final values + tail atomics
        bool hr = true;
        #pragma unroll
        for (int r = 0; r < 4; r++) {
            if (r > 0) hr = hr && (d[r] == d[r-1]);
            float fs = ms[r] + (hr ? Cs : 0.f);
            float fx = mx[r] + (hr ? Cx : 0.f);
            float fy = my[r] + (hr ? Cy : 0.f);
            float fz = mz[r] + (hr ? Cz : 0.f);
            int nd = (r < 3) ? d[r+1] : nd3;
            if (nd != d[r]) {
                float* ab = agg + ((size_t)d[r]*64 + c)*4;
                atomicAdd(ab + 0, fs);
                atomicAdd(ab + 1, fx);
                atomicAdd(ab + 2, fy);
                atomicAdd(ab + 3, fz);
            }
        }
    }
}

// ---------------------------------------------------------------------------
// Gated self-interaction + resnet; last layer fuses the energy projection
// (s@Wl1)@Wl2 == s . wl12. One wave per node, lane = channel.
// ---------------------------------------------------------------------------
__global__ __launch_bounds__(256) void node_update(
    float4* __restrict__ nf, const float4* __restrict__ agg,
    const float* __restrict__ Wg, const float* __restrict__ Ws,
    const float* __restrict__ Wv, const float* __restrict__ wl12,
    float* __restrict__ out, int do_out, int N)
{
    int wid  = (blockIdx.x * blockDim.x + threadIdx.x) >> 6;
    int lane = threadIdx.x & 63;
    if (wid >= N) return;
    size_t base = (size_t)wid * 64;
    float4 av = agg[base + lane];
    float a0 = av.x * INV_SQRT_DEG;
    float ax = av.y * INV_SQRT_DEG;
    float ay = av.z * INV_SQRT_DEG;
    float az = av.w * INV_SQRT_DEG;
    float g = 0.f, ss = 0.f, ox = 0.f, oy = 0.f, oz = 0.f;
    #pragma unroll 4
    for (int c = 0; c < 64; c++) {
        float a  = __shfl(a0, c);
        float bx = __shfl(ax, c);
        float by = __shfl(ay, c);
        float bz = __shfl(az, c);
        float wg = Wg[c*64 + lane];
        float ws = Ws[c*64 + lane];
        float wv = Wv[c*64 + lane];
        g  = fmaf(a,  wg, g);
        ss = fmaf(a,  ws, ss);
        ox = fmaf(bx, wv, ox);
        oy = fmaf(by, wv, oy);
        oz = fmaf(bz, wv, oz);
    }
    float gate = sigmoidf_(g);
    float4 cur = nf[base + lane];
    cur.x += siluf_(ss);
    cur.y += ox * gate;
    cur.z += oy * gate;
    cur.w += oz * gate;
    nf[base + lane] = cur;
    if (do_out) {
        float contrib = cur.x * wl12[lane];
        #pragma unroll
        for (int off = 32; off; off >>= 1)
            contrib += __shfl_xor(contrib, off);
        if (lane == 0) out[wid] = contrib;
    }
}

extern "C" void kernel_launch(void* const* d_in, const int* in_sizes, int n_in,
                              void* d_out, int out_size, void* d_ws, size_t ws_size,
                              hipStream_t stream)
{
    const int*   atom_type = (const int*)  d_in[0];
    const float* pos       = (const float*)d_in[1];
    const int*   src       = (const int*)  d_in[2];
    const int*   dst       = (const int*)  d_in[3];
    const float* cs        = (const float*)d_in[4];
    const float* cell      = (const float*)d_in[5];
    const int*   img       = (const int*)  d_in[6];
    const float* wlin_in   = (const float*)d_in[7];
    const float* mw1       = (const float*)d_in[8];
    const float* mb1       = (const float*)d_in[9];
    const float* mw2       = (const float*)d_in[10];
    const float* wss       = (const float*)d_in[11];
    const float* wsv       = (const float*)d_in[12];
    const float* wg        = (const float*)d_in[13];
    const float* wl1       = (const float*)d_in[14];
    const float* wl2       = (const float*)d_in[15];
    int N = in_sizes[0];
    int E = in_sizes[2];

    char* w = (char*)d_ws;
    float*  emb  = (float*)w;  w += (size_t)E * 8 * sizeof(float);     // 16.4 MB
    float4* y14  = (float4*)w; w += (size_t)E * sizeof(float4);        //  8.2 MB
    int*    srcp = (int*)w;    w += (size_t)E * sizeof(int);           //  2.0 MB
    int*    dstp = (int*)w;    w += (size_t)E * sizeof(int);           //  2.0 MB
    float4* nf   = (float4*)w; w += (size_t)N * 64 * sizeof(float4);   // 16.4 MB
    float4* agg  = (float4*)w; w += (size_t)N * 64 * sizeof(float4);   // 16.4 MB
    _Float16* w2f = (_Float16*)w; w += (size_t)3 * 20480 * sizeof(_Float16);
    float*  wl12 = (float*)w;  w += 64 * sizeof(float);
    int*    deg  = (int*)w;    w += (size_t)N * sizeof(int);
    int*    curs = (int*)w;    w += (size_t)N * sizeof(int);

    hipMemsetAsync(deg, 0, (size_t)N * sizeof(int), stream);

    count_deg<<<(E + 255) / 256, 256, 0, stream>>>(dst, deg, E);
    scan_deg<<<1, 1024, 0, stream>>>(deg, curs, N);
    transpose_w2f<<<(3 * 20480 + 255) / 256, 256, 0, stream>>>(
        mw2, w2f, wl1, wl2, wl12);
    edge_pre_scatter<<<(E + 255) / 256, 256, 0, stream>>>(
        pos, src, dst, cs, cell, img, curs, emb, y14, srcp, dstp, E);
    node_init<<<(N * 64 + 255) / 256, 256, 0, stream>>>(atom_type, wlin_in, nf, N);

    int nblocks = (E + 63) / 64;   // 256 threads = 4 waves = 64 edges / block
    for (int L = 0; L < 3; L++) {
        hipMemsetAsync(agg, 0, (size_t)N * 64 * sizeof(float4), stream);
        edge_msg_mfma<<<nblocks, 256, 0, stream>>>(
            emb, y14, srcp, dstp, nf,
            mw1 + L * 8 * 64, mb1 + L * 64, w2f + (size_t)L * 20480,
            (float*)agg, E);
        node_update<<<(N * 64 + 255) / 256, 256, 0, stream>>>(
            nf, agg, wg + L * 4096, wss + L * 4096, wsv + L * 4096,
            wl12, (float*)d_out, (L == 2) ? 1 : 0, N);
    }
}

// Round 9
// 706.498 us; speedup vs baseline: 1.6103x; 1.2525x over previous
//
#include <hip/hip_runtime.h>
#include <math.h>

#define NUM_BASIS 8
#define SQRT3 1.7320508075688772f
#define SQRT2 1.4142135623730951f
#define INV_SQRT_DEG 0.17677669529663687f   // 1/sqrt(32)
#define PI_F 3.14159265358979323846f

typedef _Float16 half8 __attribute__((ext_vector_type(8)));
typedef float float4v __attribute__((ext_vector_type(4)));

__device__ __forceinline__ float sigmoidf_(float x) { return 1.0f / (1.0f + __expf(-x)); }
__device__ __forceinline__ float siluf_(float x) { return x * sigmoidf_(x); }

// ---------------------------------------------------------------------------
// CSR build: degree count -> single-block shfl scan -> fused geometry+scatter
// ---------------------------------------------------------------------------
__global__ __launch_bounds__(256) void count_deg(
    const int* __restrict__ dst, int* __restrict__ deg, int E)
{
    int e = blockIdx.x * blockDim.x + threadIdx.x;
    if (e < E) atomicAdd(&deg[dst[e]], 1);
}

__global__ __launch_bounds__(1024) void scan_deg(
    const int* __restrict__ deg, int* __restrict__ cursor, int N)
{
    __shared__ int wsum[16];
    __shared__ int carry_s, tot_s;
    int tid = threadIdx.x;
    int wid = tid >> 6, lane = tid & 63;
    if (tid == 0) carry_s = 0;
    __syncthreads();
    for (int base = 0; base < N; base += 1024) {
        int i = base + tid;
        int v = (i < N) ? deg[i] : 0;
        int incl = v;
        #pragma unroll
        for (int off = 1; off < 64; off <<= 1) {
            int t = __shfl_up(incl, off);
            if (lane >= off) incl += t;
        }
        if (lane == 63) wsum[wid] = incl;
        __syncthreads();
        if (wid == 0 && lane < 16) {
            int wv = wsum[lane];
            int wincl = wv;
            #pragma unroll
            for (int off = 1; off < 16; off <<= 1) {
                int t = __shfl_up(wincl, off);
                if (lane >= off) wincl += t;
            }
            wsum[lane] = wincl - wv;        // exclusive wave offset
            if (lane == 15) tot_s = wincl;  // chunk total
        }
        __syncthreads();
        int carry = carry_s;
        if (i < N) cursor[i] = carry + wsum[wid] + incl - v;
        __syncthreads();
        if (tid == 0) carry_s = carry + tot_s;
        __syncthreads();
    }
}

// Per-edge geometry + radial embedding, scattered directly into CSR slots.
__global__ __launch_bounds__(256) void edge_pre_scatter(
    const float* __restrict__ pos, const int* __restrict__ src,
    const int* __restrict__ dst, const float* __restrict__ cs,
    const float* __restrict__ cell, const int* __restrict__ img,
    int* __restrict__ cursor, float* __restrict__ emb,
    float4* __restrict__ y14, int* __restrict__ srcp,
    int* __restrict__ dstp, int E)
{
    int e = blockIdx.x * blockDim.x + threadIdx.x;
    if (e >= E) return;
    int si = src[e], di = dst[e];
    int slot = atomicAdd(&cursor[di], 1);
    srcp[slot] = si;
    dstp[slot] = di;
    float vx = pos[di*3+0] - pos[si*3+0];
    float vy = pos[di*3+1] - pos[si*3+1];
    float vz = pos[di*3+2] - pos[si*3+2];
    float c0 = cs[(size_t)e*3+0], c1 = cs[(size_t)e*3+1], c2 = cs[(size_t)e*3+2];
    const float* M = cell + (size_t)img[si] * 9;
    vx += c0*M[0] + c1*M[3] + c2*M[6];
    vy += c0*M[1] + c1*M[4] + c2*M[7];
    vz += c0*M[2] + c1*M[5] + c2*M[8];
    float r  = sqrtf(vx*vx + vy*vy + vz*vz);
    float rs = fmaxf(r, 1e-9f);
    float inv = 1.0f / rs;
    y14[slot] = make_float4(SQRT3*vx*inv, SQRT3*vy*inv, SQRT3*vz*inv, 0.0f);
    // polynomial cutoff p=6: 1 - 28 x^6 + 48 x^7 - 21 x^8 (0 for x>=1)
    float x = r * (1.0f / 5.0f);
    float x2 = x*x, x6 = x2*x2*x2;
    float fc = 1.0f - 28.0f*x6 + 48.0f*x6*x - 21.0f*x6*x2;
    if (x >= 1.0f) fc = 0.0f;
    float pre = sqrtf(2.0f / 5.0f) * inv * fc;
    float t = PI_F * rs * (1.0f / 5.0f);
    #pragma unroll
    for (int n = 1; n <= NUM_BASIS; n++)
        emb[(size_t)slot*NUM_BASIS + (n-1)] = pre * __sinf((float)n * t);
}

// ---------------------------------------------------------------------------
// W2 (3,64,320) fp32 -> f16 MFMA B-fragment order; also wl12 = Wl1 @ Wl2.
// w2f[((((L*4+cg)*5+p)*2+kh)*64+lane)*8+j] = W2[L][k][n]
//   k = kh*32 + (lane>>4)*8 + j,  n = p*64 + cg*16 + (lane&15)
// ---------------------------------------------------------------------------
__global__ __launch_bounds__(256) void transpose_w2f(
    const float* __restrict__ W2, _Float16* __restrict__ w2f,
    const float* __restrict__ Wl1, const float* __restrict__ Wl2,
    float* __restrict__ wl12)
{
    int idx = blockIdx.x * blockDim.x + threadIdx.x;
    if (idx < 64) {
        float a = 0.f;
        #pragma unroll
        for (int j = 0; j < 16; j++) a = fmaf(Wl1[idx*16 + j], Wl2[j], a);
        wl12[idx] = a;
    }
    if (idx >= 3 * 20480) return;
    int L  = idx / 20480;
    int r  = idx % 20480;
    int cg = r / 5120;
    int r2 = r % 5120;
    int p  = r2 / 1024;
    int r3 = r2 % 1024;
    int kh = r3 / 512;
    int r4 = r3 % 512;
    int lane = r4 / 8;
    int j  = r4 % 8;
    int k = kh*32 + (lane >> 4)*8 + j;
    int n = p*64 + cg*16 + (lane & 15);
    w2f[idx] = (_Float16)W2[(size_t)L*20480 + k*320 + n];
}

// ---------------------------------------------------------------------------
// nf[n*64 + c] = (s, vx, vy, vz) AoS. Init s from w_lin_in, v = 0.
// ---------------------------------------------------------------------------
__global__ __launch_bounds__(256) void node_init(
    const int* __restrict__ type, const float* __restrict__ wlin,
    float4* __restrict__ nf, int N)
{
    int i = blockIdx.x * blockDim.x + threadIdx.x;
    if (i >= N * 64) return;
    int n = i >> 6, c = i & 63;
    nf[i] = make_float4(wlin[(size_t)type[n]*64 + c], 0.f, 0.f, 0.f);
}

// ---------------------------------------------------------------------------
// MFMA edge kernel: one wave per 16 CSR-consecutive edges (R6 operating
// point: VGPR~60, ~40% occupancy — latency-hiding beats per-wave efficiency;
// R7's 64-edge/wave variant regressed 46% via VGPR=160/occ=11%).
// agg is PLANAR (4 arrays): tail atomics from 16 lanes hit 64 contiguous
// bytes per component = 2 full 32B sectors, vs 8 half-used sectors with AoS
// (R8: atomic RMW sector traffic ~370 MB of 400 MB HBM bytes).
// Do NOT cap VGPRs (R4: spill catastrophe).
// ---------------------------------------------------------------------------
__global__ __launch_bounds__(256) void edge_msg_mfma(
    const float* __restrict__ emb, const float4* __restrict__ y14,
    const int* __restrict__ srcp, const int* __restrict__ dstp,
    const float4* __restrict__ nf,
    const float* __restrict__ W1, const float* __restrict__ B1,
    const _Float16* __restrict__ w2f,
    float* __restrict__ aggs, float* __restrict__ aggx,
    float* __restrict__ aggy, float* __restrict__ aggz, int E)
{
    int wave  = (blockIdx.x * blockDim.x + threadIdx.x) >> 6;
    int lane  = threadIdx.x & 63;
    int wbase = wave * 16;
    if (wbase >= E) return;
    int q   = lane >> 4;     // quad: selects 4-edge row group / k-slice
    int col = lane & 15;     // column: A-edge index / output channel idx

    // ---- A-fragments: h[k] for edge (wbase+col), k = kh*32 + q*8 + j ----
    half8 afrag[2];
    {
        int eA = wbase + col;
        float4 ea = *(const float4*)(emb + (size_t)eA*8);
        float4 eb2 = *(const float4*)(emb + (size_t)eA*8 + 4);
        float em[8] = {ea.x, ea.y, ea.z, ea.w, eb2.x, eb2.y, eb2.z, eb2.w};
        #pragma unroll
        for (int kh = 0; kh < 2; kh++) {
            int kb = kh*32 + q*8;
            float hv[8];
            float4 b0 = *(const float4*)(B1 + kb);
            float4 b1 = *(const float4*)(B1 + kb + 4);
            hv[0]=b0.x; hv[1]=b0.y; hv[2]=b0.z; hv[3]=b0.w;
            hv[4]=b1.x; hv[5]=b1.y; hv[6]=b1.z; hv[7]=b1.w;
            #pragma unroll
            for (int jj = 0; jj < 8; jj++) {
                float4 wa = *(const float4*)(W1 + jj*64 + kb);
                float4 wb = *(const float4*)(W1 + jj*64 + kb + 4);
                hv[0] = fmaf(em[jj], wa.x, hv[0]);
                hv[1] = fmaf(em[jj], wa.y, hv[1]);
                hv[2] = fmaf(em[jj], wa.z, hv[2]);
                hv[3] = fmaf(em[jj], wa.w, hv[3]);
                hv[4] = fmaf(em[jj], wb.x, hv[4]);
                hv[5] = fmaf(em[jj], wb.y, hv[5]);
                hv[6] = fmaf(em[jj], wb.z, hv[6]);
                hv[7] = fmaf(em[jj], wb.w, hv[7]);
            }
            #pragma unroll
            for (int j = 0; j < 8; j++)
                afrag[kh][j] = (_Float16)siluf_(hv[j]);
        }
    }

    // ---- per-quad edge metadata (4 edges eb..eb+3, same for 16 lanes) ----
    int eb = wbase + q*4;
    int d[4], si[4];
    float4 y1v[4];
    #pragma unroll
    for (int r = 0; r < 4; r++) {
        d[r]   = dstp[eb + r];
        si[r]  = srcp[eb + r];
        y1v[r] = y14[eb + r];
    }
    int dnq = __shfl_down(d[0], 16);      // next quad's first dst
    int nd3 = (q == 3) ? -1 : dnq;        // q3 reg3: forced tail (cross-wave via atomic)
    int df = d[0], dl = d[3];
    bool U = (df == dl);
    int dlp = __shfl_up(dl, 16);
    bool link = (q > 0) && (dlp == df);

    // ---- channel groups of 16 ----
    #pragma unroll 1
    for (int cg = 0; cg < 4; cg++) {
        float4v acc[5];
        #pragma unroll
        for (int p = 0; p < 5; p++) acc[p] = (float4v){0.f, 0.f, 0.f, 0.f};
        const _Float16* wbp = w2f + ((size_t)cg*5*2*64*8) + (size_t)lane*8;
        #pragma unroll
        for (int p = 0; p < 5; p++) {
            half8 bf0 = *(const half8*)(wbp + ((size_t)(p*2 + 0))*64*8);
            half8 bf1 = *(const half8*)(wbp + ((size_t)(p*2 + 1))*64*8);
            acc[p] = __builtin_amdgcn_mfma_f32_16x16x32_f16(afrag[0], bf0, acc[p], 0, 0, 0);
            acc[p] = __builtin_amdgcn_mfma_f32_16x16x32_f16(afrag[1], bf1, acc[p], 0, 0, 0);
        }
        int c = cg*16 + col;

        // message math per reg-edge (C-layout: acc[p][r] = w_p(edge eb+r, c))
        float ms[4], mx[4], my[4], mz[4];
        #pragma unroll
        for (int r = 0; r < 4; r++) {
            float4 f = nf[(size_t)si[r]*64 + c];
            float yx = y1v[r].x, yy = y1v[r].y, yz = y1v[r].z;
            float w1 = acc[0][r], w2 = acc[1][r], w3 = acc[2][r];
            float w4 = acc[3][r], w5 = acc[4][r];
            float vdoty = f.y*yx + f.z*yy + f.w*yz;
            ms[r] = w1*f.x + w2*vdoty*(1.0f/SQRT3);
            float cx = f.z*yz - f.w*yy;
            float cy = f.w*yx - f.y*yz;
            float cz = f.y*yy - f.z*yx;
            mx[r] = w3*f.x*yx + w4*f.y + w5*cx*(1.0f/SQRT2);
            my[r] = w3*f.x*yy + w4*f.z + w5*cy*(1.0f/SQRT2);
            mz[r] = w3*f.x*yz + w4*f.w + w5*cz*(1.0f/SQRT2);
        }
        // in-lane segmented inclusive scan over the 4 reg-edges
        #pragma unroll
        for (int r = 1; r < 4; r++) {
            if (d[r] == d[r-1]) {
                ms[r] += ms[r-1]; mx[r] += mx[r-1];
                my[r] += my[r-1]; mz[r] += mz[r-1];
            }
        }
        // cross-quad carry (chains up to 4 quads -> 3 iterations)
        float Cs = 0.f, Cx = 0.f, Cy = 0.f, Cz = 0.f;
        #pragma unroll
        for (int it = 0; it < 3; it++) {
            float es = ms[3] + (U ? Cs : 0.f);
            float ex = mx[3] + (U ? Cx : 0.f);
            float ey = my[3] + (U ? Cy : 0.f);
            float ez = mz[3] + (U ? Cz : 0.f);
            float ts = __shfl_up(es, 16);
            float tx = __shfl_up(ex, 16);
            float ty = __shfl_up(ey, 16);
            float tz = __shfl_up(ez, 16);
            Cs = link ? ts : 0.f; Cx = link ? tx : 0.f;
            Cy = link ? ty : 0.f; Cz = link ? tz : 0.f;
        }
        // final values + tail atomics (planar: 64B contiguous per component)
        bool hr = true;
        #pragma unroll
        for (int r = 0; r < 4; r++) {
            if (r > 0) hr = hr && (d[r] == d[r-1]);
            float fs = ms[r] + (hr ? Cs : 0.f);
            float fx = mx[r] + (hr ? Cx : 0.f);
            float fy = my[r] + (hr ? Cy : 0.f);
            float fz = mz[r] + (hr ? Cz : 0.f);
            int nd = (r < 3) ? d[r+1] : nd3;
            if (nd != d[r]) {
                size_t ai = (size_t)d[r]*64 + c;
                atomicAdd(aggs + ai, fs);
                atomicAdd(aggx + ai, fx);
                atomicAdd(aggy + ai, fy);
                atomicAdd(aggz + ai, fz);
            }
        }
    }
}

// ---------------------------------------------------------------------------
// Gated self-interaction + resnet; last layer fuses the energy projection
// (s@Wl1)@Wl2 == s . wl12. One wave per node, lane = channel.
// ---------------------------------------------------------------------------
__global__ __launch_bounds__(256) void node_update(
    float4* __restrict__ nf,
    const float* __restrict__ aggs, const float* __restrict__ aggx,
    const float* __restrict__ aggy, const float* __restrict__ aggz,
    const float* __restrict__ Wg, const float* __restrict__ Ws,
    const float* __restrict__ Wv, const float* __restrict__ wl12,
    float* __restrict__ out, int do_out, int N)
{
    int wid  = (blockIdx.x * blockDim.x + threadIdx.x) >> 6;
    int lane = threadIdx.x & 63;
    if (wid >= N) return;
    size_t base = (size_t)wid * 64;
    float a0 = aggs[base + lane] * INV_SQRT_DEG;
    float ax = aggx[base + lane] * INV_SQRT_DEG;
    float ay = aggy[base + lane] * INV_SQRT_DEG;
    float az = aggz[base + lane] * INV_SQRT_DEG;
    float g = 0.f, ss = 0.f, ox = 0.f, oy = 0.f, oz = 0.f;
    #pragma unroll 4
    for (int c = 0; c < 64; c++) {
        float a  = __shfl(a0, c);
        float bx = __shfl(ax, c);
        float by = __shfl(ay, c);
        float bz = __shfl(az, c);
        float wg = Wg[c*64 + lane];
        float ws = Ws[c*64 + lane];
        float wv = Wv[c*64 + lane];
        g  = fmaf(a,  wg, g);
        ss = fmaf(a,  ws, ss);
        ox = fmaf(bx, wv, ox);
        oy = fmaf(by, wv, oy);
        oz = fmaf(bz, wv, oz);
    }
    float gate = sigmoidf_(g);
    float4 cur = nf[base + lane];
    cur.x += siluf_(ss);
    cur.y += ox * gate;
    cur.z += oy * gate;
    cur.w += oz * gate;
    nf[base + lane] = cur;
    if (do_out) {
        float contrib = cur.x * wl12[lane];
        #pragma unroll
        for (int off = 32; off; off >>= 1)
            contrib += __shfl_xor(contrib, off);
        if (lane == 0) out[wid] = contrib;
    }
}

extern "C" void kernel_launch(void* const* d_in, const int* in_sizes, int n_in,
                              void* d_out, int out_size, void* d_ws, size_t ws_size,
                              hipStream_t stream)
{
    const int*   atom_type = (const int*)  d_in[0];
    const float* pos       = (const float*)d_in[1];
    const int*   src       = (const int*)  d_in[2];
    const int*   dst       = (const int*)  d_in[3];
    const float* cs        = (const float*)d_in[4];
    const float* cell      = (const float*)d_in[5];
    const int*   img       = (const int*)  d_in[6];
    const float* wlin_in   = (const float*)d_in[7];
    const float* mw1       = (const float*)d_in[8];
    const float* mb1       = (const float*)d_in[9];
    const float* mw2       = (const float*)d_in[10];
    const float* wss       = (const float*)d_in[11];
    const float* wsv       = (const float*)d_in[12];
    const float* wg        = (const float*)d_in[13];
    const float* wl1       = (const float*)d_in[14];
    const float* wl2       = (const float*)d_in[15];
    int N = in_sizes[0];
    int E = in_sizes[2];

    char* w = (char*)d_ws;
    float*  emb  = (float*)w;  w += (size_t)E * 8 * sizeof(float);     // 16.4 MB
    float4* y14  = (float4*)w; w += (size_t)E * sizeof(float4);        //  8.2 MB
    int*    srcp = (int*)w;    w += (size_t)E * sizeof(int);           //  2.0 MB
    int*    dstp = (int*)w;    w += (size_t)E * sizeof(int);           //  2.0 MB
    float4* nf   = (float4*)w; w += (size_t)N * 64 * sizeof(float4);   // 16.4 MB
    float*  agg  = (float*)w;  w += (size_t)N * 64 * 4 * sizeof(float);// 16.4 MB planar
    _Float16* w2f = (_Float16*)w; w += (size_t)3 * 20480 * sizeof(_Float16);
    float*  wl12 = (float*)w;  w += 64 * sizeof(float);
    int*    deg  = (int*)w;    w += (size_t)N * sizeof(int);
    int*    curs = (int*)w;    w += (size_t)N * sizeof(int);

    size_t NC = (size_t)N * 64;
    float* aggs = agg;
    float* aggx = agg + NC;
    float* aggy = agg + 2*NC;
    float* aggz = agg + 3*NC;

    hipMemsetAsync(deg, 0, (size_t)N * sizeof(int), stream);

    count_deg<<<(E + 255) / 256, 256, 0, stream>>>(dst, deg, E);
    scan_deg<<<1, 1024, 0, stream>>>(deg, curs, N);
    transpose_w2f<<<(3 * 20480 + 255) / 256, 256, 0, stream>>>(
        mw2, w2f, wl1, wl2, wl12);
    edge_pre_scatter<<<(E + 255) / 256, 256, 0, stream>>>(
        pos, src, dst, cs, cell, img, curs, emb, y14, srcp, dstp, E);
    node_init<<<(N * 64 + 255) / 256, 256, 0, stream>>>(atom_type, wlin_in, nf, N);

    int nblocks = (E + 63) / 64;   // 256 threads = 4 waves = 64 edges / block
    for (int L = 0; L < 3; L++) {
        hipMemsetAsync(agg, 0, NC * 4 * sizeof(float), stream);
        edge_msg_mfma<<<nblocks, 256, 0, stream>>>(
            emb, y14, srcp, dstp, nf,
            mw1 + L * 8 * 64, mb1 + L * 64, w2f + (size_t)L * 20480,
            aggs, aggx, aggy, aggz, E);
        node_update<<<(N * 64 + 255) / 256, 256, 0, stream>>>(
            nf, aggs, aggx, aggy, aggz,
            wg + L * 4096, wss + L * 4096, wsv + L * 4096,
            wl12, (float*)d_out, (L == 2) ? 1 : 0, N);
    }
}